// Round 9
// baseline (162.837 us; speedup 1.0000x reference)
//
#include <hip/hip_runtime.h>
#include <hip/hip_bf16.h>

typedef __attribute__((ext_vector_type(8))) short short8;
typedef __attribute__((ext_vector_type(4))) float floatx4;

#define N_ROWS   16384
#define IN_DIM   512
#define OUT_DIM  512
#define K_SPLINE 4096
#define K_TOT    4608
#define NKT      72              /* 64-k half-periods  */
#define NPER     36              /* 128-k barrier periods */
#define NSPER    32              /* spline periods (4096/128) */
#define NKTILE   144             /* 32-wide k-tiles */
#define L2E      1.4426950408889634f
#define C2E      0.13533528323661270f   /* exp(-2) */

__device__ __forceinline__ unsigned short f2bf(float f) {
    unsigned int u = __float_as_uint(f);
    unsigned int r = u + 0x7FFFu + ((u >> 16) & 1u);
    return (unsigned short)(r >> 16);
}

// truncating pack: two fp32 -> two bf16 in one v_perm_b32 (A-side only; B rounded in prep)
__device__ __forceinline__ unsigned packtrunc(float f0, float f1) {
    return __builtin_amdgcn_perm(__float_as_uint(f1), __float_as_uint(f0), 0x07060302);
}

// lgkm-only barrier: LDS ordering preserved; wave-private global loads stay
// in flight across the barrier (essential for the deep B pipeline).
__device__ __forceinline__ void barrier_lgkm() {
    asm volatile("s_waitcnt lgkmcnt(0)\n\ts_barrier" ::: "memory");
}

// ---------------------------------------------------------------------------
// prep: B in MFMA B-fragment-tiled layout (16x16x32).
// frag idx = (ct*NKTILE + kt32)*64 + lane ; elem j:
//   n = ct*16 + (lane&15), k = kt32*32 + (lane>>4)*8 + j
// ---------------------------------------------------------------------------
__global__ __launch_bounds__(256) void prep_kernel(
    const float* __restrict__ sw, const float* __restrict__ bw,
    unsigned short* __restrict__ Btf)
{
    const int t     = threadIdx.x;
    const int lane  = t & 63;
    const int kt32  = blockIdx.x * 4 + (t >> 6);
    const int ct    = blockIdx.y;
    const int mn    = lane & 15, q = lane >> 4;
    const int n     = ct * 16 + mn;
    const int kbase = kt32 * 32 + q * 8;
    short8 v;
    if (kbase < K_SPLINE) {
        #pragma unroll
        for (int j = 0; j < 8; ++j)
            v[j] = (short)f2bf(sw[(size_t)(kbase + j) * OUT_DIM + n]);
    } else {
        #pragma unroll
        for (int j = 0; j < 8; ++j)
            v[j] = (short)f2bf(bw[(size_t)n * IN_DIM + (kbase + j - K_SPLINE)]);
    }
    reinterpret_cast<short8*>(Btf)[(size_t)(ct * NKTILE + kt32) * 64 + lane] = v;
}

// ---------------------------------------------------------------------------
// 8 basis values of one x -> packed uint4 (bf16 x8)
// ---------------------------------------------------------------------------
__device__ __forceinline__ uint4 basis_pack(float X) {
    const float u = fmaf(1.75f, X, 3.5f);
    float b = __builtin_amdgcn_exp2f(-(u * u) * L2E);            // exp(-u^2)
    float r = __builtin_amdgcn_exp2f(fmaf(2.0f * L2E, u, -L2E)); // exp(2u-1)
    float v[8];
    v[0] = b;
    #pragma unroll
    for (int j = 1; j < 8; ++j) { b *= r; r *= C2E; v[j] = b; }
    uint4 p;
    p.x = packtrunc(v[0], v[1]);
    p.y = packtrunc(v[2], v[3]);
    p.z = packtrunc(v[4], v[5]);
    p.w = packtrunc(v[6], v[7]);
    return p;
}

// ---------------------------------------------------------------------------
// Stage one 64x128 A-tile (period p) into swizzled LDS — 512-thread map.
// Row stride 128 ushort; 16B blocks, stored blk = i ^ (row&15).
// Thread covers row rowA = tid>>3, blocks i = colq*2, colq*2+1 (colq = tid&7).
// ---------------------------------------------------------------------------
__device__ __forceinline__ void stageA128(unsigned short* dst, const float* xrow,
                                          int rowA, int colq, int p, float2 xsp)
{
    unsigned short* arow = dst + rowA * 128;
    if (p < NSPER) {
        const float xv[2] = {xsp.x, xsp.y};
        #pragma unroll
        for (int e = 0; e < 2; ++e) {
            const uint4 pk = basis_pack(xv[e]);
            const int blk = (colq * 2 + e) ^ (rowA & 15);
            *reinterpret_cast<uint4*>(arow + blk * 8) = pk;
        }
    } else {
        const float* xs = xrow + (p - NSPER) * 128 + colq * 16;
        #pragma unroll
        for (int e = 0; e < 2; ++e) {
            const float4 a0 = *reinterpret_cast<const float4*>(xs + e * 8);
            const float4 a1 = *reinterpret_cast<const float4*>(xs + e * 8 + 4);
            const float f[8] = {a0.x, a0.y, a0.z, a0.w, a1.x, a1.y, a1.z, a1.w};
            float s[8];
            #pragma unroll
            for (int j = 0; j < 8; ++j)
                s[j] = f[j] * __builtin_amdgcn_rcpf(
                    1.0f + __builtin_amdgcn_exp2f(-f[j] * L2E));
            uint4 pk;
            pk.x = packtrunc(s[0], s[1]);
            pk.y = packtrunc(s[2], s[3]);
            pk.z = packtrunc(s[4], s[5]);
            pk.w = packtrunc(s[6], s[7]);
            const int blk = (colq * 2 + e) ^ (rowA & 15);
            *reinterpret_cast<uint4*>(arow + blk * 8) = pk;
        }
    }
}

// B fragment load for one 64-k half-period (kt): 4 nt x 2 s
template<bool PREP>
__device__ __forceinline__ void load_bfrags(short8 dst[4][2], const short8* __restrict__ Bf,
                                            const unsigned* bbase, int kt,
                                            const float* __restrict__ sw,
                                            const float* __restrict__ bw,
                                            int col0, int lane)
{
    if (kt >= NKT) return;
    if (PREP) {
        #pragma unroll
        for (int nt = 0; nt < 4; ++nt)
            #pragma unroll
            for (int s = 0; s < 2; ++s)
                dst[nt][s] = Bf[bbase[nt] + (unsigned)(kt * 2 + s) * 64u];
    } else {
        const int mn = lane & 15, q = lane >> 4;
        #pragma unroll
        for (int nt = 0; nt < 4; ++nt) {
            const int n = col0 + nt * 16 + mn;
            #pragma unroll
            for (int s = 0; s < 2; ++s) {
                short8 v;
                #pragma unroll
                for (int j = 0; j < 8; ++j) {
                    const int k = (kt * 2 + s) * 32 + q * 8 + j;
                    const float val = (k < K_SPLINE)
                        ? sw[(size_t)k * OUT_DIM + n]
                        : bw[(size_t)n * IN_DIM + (k - K_SPLINE)];
                    v[j] = (short)f2bf(val);
                }
                dst[nt][s] = v;
            }
        }
    }
}

// One 128-k period. PAR = LDS parity (literal). U0/U1 = B buffers consumed
// (first/second 64-k half), L0/L1 = B buffers loaded for period PP+1.
// All buffer indices are compile-time literals (rule #20; no lambdas — R7's
// by-ref lambda made acc/bb addressable -> scratch).
#define KAN_PERIOD(PP, PAR, U0, U1, L0, L1)                                   \
  {                                                                           \
    const unsigned short* Acur = &Als[PAR][0];                                \
    load_bfrags<PREP>(bb[L0], Bf, bbase, 2 * (PP) + 2, sw, bw, col0, lane);   \
    if ((PP) + 1 < NPER) {                                                    \
        stageA128(&Als[(PAR) ^ 1][0], xrow, rowA, colq, (PP) + 1, xsp);       \
        if ((PP) + 2 < NSPER)                                                 \
            xsp = *reinterpret_cast<const float2*>(                           \
                xrow + ((PP) + 2) * 16 + colq * 2);                           \
    }                                                                         \
    _Pragma("unroll")                                                         \
    for (int s = 0; s < 2; ++s) {                                             \
        const int st = s;                                                     \
        short8 af[4];                                                         \
        _Pragma("unroll")                                                     \
        for (int mt = 0; mt < 4; ++mt) {                                      \
            const int r = mt * 16 + mn;                                       \
            af[mt] = *reinterpret_cast<const short8*>(                        \
                Acur + r * 128 + (((st * 4 + q) ^ (r & 15)) * 8));            \
        }                                                                     \
        _Pragma("unroll")                                                     \
        for (int mt = 0; mt < 4; ++mt)                                        \
            _Pragma("unroll")                                                 \
            for (int nt = 0; nt < 4; ++nt)                                    \
                acc[mt][nt] = __builtin_amdgcn_mfma_f32_16x16x32_bf16(        \
                    af[mt], bb[U0][nt][s], acc[mt][nt], 0, 0, 0);             \
    }                                                                         \
    load_bfrags<PREP>(bb[L1], Bf, bbase, 2 * (PP) + 3, sw, bw, col0, lane);   \
    _Pragma("unroll")                                                         \
    for (int s = 0; s < 2; ++s) {                                             \
        const int st = 2 + s;                                                 \
        short8 af[4];                                                         \
        _Pragma("unroll")                                                     \
        for (int mt = 0; mt < 4; ++mt) {                                      \
            const int r = mt * 16 + mn;                                       \
            af[mt] = *reinterpret_cast<const short8*>(                        \
                Acur + r * 128 + (((st * 4 + q) ^ (r & 15)) * 8));            \
        }                                                                     \
        _Pragma("unroll")                                                     \
        for (int mt = 0; mt < 4; ++mt)                                        \
            _Pragma("unroll")                                                 \
            for (int nt = 0; nt < 4; ++nt)                                    \
                acc[mt][nt] = __builtin_amdgcn_mfma_f32_16x16x32_bf16(        \
                    af[mt], bb[U1][nt][s], acc[mt][nt], 0, 0, 0);             \
    }                                                                         \
    barrier_lgkm();                                                           \
  }

// ---------------------------------------------------------------------------
// Fused KAN — R2/R8 machinery + depth-2 B prefetch (4 half-period reg buffers,
// each B batch issued a FULL period before first use -> ~2x bytes in flight).
// 256 blocks x 8 waves, block tile 64x512 (d=1), wave tile 64x64,
// A LDS dbuf 2x16KB, lgkm-only barrier (1 per period).
// ---------------------------------------------------------------------------
template<bool PREP>
__global__ __launch_bounds__(512, 2) void kan_kernel(
    const float* __restrict__ x,
    const unsigned short* __restrict__ Btf,
    const float* __restrict__ sw,
    const float* __restrict__ bw,
    const float* __restrict__ bias,
    float* __restrict__ out)
{
    __shared__ unsigned short Als[2][64 * 128];   // 2 x 16 KB

    const int tid  = threadIdx.x;
    const int wn   = tid >> 6;          // wave -> 64-col group (0..7)
    const int lane = tid & 63;
    const int q    = lane >> 4;
    const int mn   = lane & 15;
    const int bid  = blockIdx.x;
    const int row0 = bid * 64;
    const int col0 = wn * 64;

    const int rowA = tid >> 3;          // 0..63
    const int colq = tid & 7;           // 0..7
    const float* xrow = x + (size_t)(row0 + rowA) * IN_DIM;

    unsigned bbase[4];
    #pragma unroll
    for (int nt = 0; nt < 4; ++nt)
        bbase[nt] = (unsigned)(((col0 >> 4) + nt) * NKTILE) * 64u + (unsigned)lane;
    const short8* Bf = reinterpret_cast<const short8*>(Btf);

    floatx4 acc[4][4];
    #pragma unroll
    for (int i = 0; i < 4; ++i)
        #pragma unroll
        for (int j = 0; j < 4; ++j)
            acc[i][j] = (floatx4){0.f, 0.f, 0.f, 0.f};

    short8 bb[4][4][2];   // 4 half-period B buffers (ring), literal-indexed

    // prologue: stage p=0; preload B for kt=0 AND kt=1; spline x for p=1
    float2 xsp = *reinterpret_cast<const float2*>(xrow + colq * 2);
    stageA128(&Als[0][0], xrow, rowA, colq, 0, xsp);
    load_bfrags<PREP>(bb[0], Bf, bbase, 0, sw, bw, col0, lane);
    load_bfrags<PREP>(bb[1], Bf, bbase, 1, sw, bw, col0, lane);
    xsp = *reinterpret_cast<const float2*>(xrow + 16 + colq * 2);
    __syncthreads();

    #pragma unroll 1
    for (int p = 0; p < NPER; p += 2) {
        KAN_PERIOD(p,     0, 0, 1, 2, 3)   // uses bb[0],bb[1]; loads bb[2],bb[3]
        KAN_PERIOD(p + 1, 1, 2, 3, 0, 1)   // uses bb[2],bb[3]; loads bb[0],bb[1]
    }

    // epilogue: + bias, store fp32
    #pragma unroll
    for (int nt = 0; nt < 4; ++nt) {
        const int col = col0 + nt * 16 + mn;
        const float bv = bias[col];
        #pragma unroll
        for (int mt = 0; mt < 4; ++mt) {
            const int rb = row0 + mt * 16 + q * 4;
            #pragma unroll
            for (int e = 0; e < 4; ++e)
                out[(size_t)(rb + e) * OUT_DIM + col] = acc[mt][nt][e] + bv;
        }
    }
}

extern "C" void kernel_launch(void* const* d_in, const int* in_sizes, int n_in,
                              void* d_out, int out_size, void* d_ws, size_t ws_size,
                              hipStream_t stream)
{
    const float* x    = (const float*)d_in[0];
    // d_in[1] = grid (linspace(-2,2,8)) — folded into constants
    const float* sw   = (const float*)d_in[2];
    const float* bw   = (const float*)d_in[3];
    const float* bias = (const float*)d_in[4];
    float* out = (float*)d_out;

    const size_t bt_bytes = (size_t)OUT_DIM * K_TOT * sizeof(unsigned short);
    if (ws_size >= bt_bytes) {
        unsigned short* Btf = (unsigned short*)d_ws;
        prep_kernel<<<dim3(NKTILE / 4, OUT_DIM / 16), 256, 0, stream>>>(sw, bw, Btf);
        kan_kernel<true><<<dim3(256), 512, 0, stream>>>(
            x, Btf, sw, bw, bias, out);
    } else {
        kan_kernel<false><<<dim3(256), 512, 0, stream>>>(
            x, nullptr, sw, bw, bias, out);
    }
}